// Round 1
// baseline (264.641 us; speedup 1.0000x reference)
//
#include <hip/hip_runtime.h>
#include <math.h>

#define BATCH 4
#define CH    256   // feature channels == depth of sampled volume
#define HH    128
#define WW    128
#define PC    256   // para channels
#define PI_F  3.14159f

// ---------------------------------------------------------------------------
// Kernel 1: per-(b,c) affine parameters.
// grid = BATCH blocks, 256 threads. Thread j handles output channel j.
// Phase 1: p = relu(para_code @ W1 + b1) into shared.
// Phase 2: scale/angle/translation heads -> params[b*CH+c] = {s*ca, s*sa, tx, ty}
// ---------------------------------------------------------------------------
__global__ __launch_bounds__(256)
void adaat_params_kernel(const float* __restrict__ para_code,
                         const float* __restrict__ W1, const float* __restrict__ b1,
                         const float* __restrict__ Ws, const float* __restrict__ bs,
                         const float* __restrict__ Wr, const float* __restrict__ br,
                         const float* __restrict__ Wt, const float* __restrict__ bt,
                         float4* __restrict__ params) {
    const int b = blockIdx.x;
    const int j = threadIdx.x;          // 0..255
    __shared__ float pc_sh[PC];
    __shared__ float p_sh[PC];

    pc_sh[j] = para_code[b * PC + j];
    __syncthreads();

    float acc = b1[j];
#pragma unroll 8
    for (int k = 0; k < PC; ++k)
        acc = fmaf(pc_sh[k], W1[k * PC + j], acc);   // W1[k][j], coalesced over j
    p_sh[j] = fmaxf(acc, 0.0f);
    __syncthreads();

    float as  = bs[j];
    float ar  = br[j];
    float at0 = bt[2 * j];
    float at1 = bt[2 * j + 1];
#pragma unroll 4
    for (int k = 0; k < PC; ++k) {
        const float pk = p_sh[k];
        as  = fmaf(pk, Ws[k * CH + j],          as);
        ar  = fmaf(pk, Wr[k * CH + j],          ar);
        at0 = fmaf(pk, Wt[k * 2 * CH + 2 * j],     at0);
        at1 = fmaf(pk, Wt[k * 2 * CH + 2 * j + 1], at1);
    }

    const float s   = 2.0f / (1.0f + expf(-as));   // sigmoid * 2
    const float ang = tanhf(ar) * PI_F;
    const float tx  = tanhf(at0);
    const float ty  = tanhf(at1);
    float sa, ca;
    sincosf(ang, &sa, &ca);
    params[b * CH + j] = make_float4(s * ca, s * sa, tx, ty);
}

// ---------------------------------------------------------------------------
// Kernel 2: trilinear grid_sample (padding_mode='zeros', align_corners=False).
// One thread per output pixel. Block = 256 threads = 2 output rows.
// grid = BATCH*CH*(HH/2) blocks; consecutive blocks share the same (b,c)
// plane (64 blocks/plane) for L2/L3 locality.
// ---------------------------------------------------------------------------
__global__ __launch_bounds__(256)
void adaat_sample_kernel(const float* __restrict__ fm,
                         const float4* __restrict__ params,
                         float* __restrict__ out) {
    const int bid = blockIdx.x;
    const int hp  = bid & 63;                 // h-pair index (64 per plane)
    const int c   = (bid >> 6) & (CH - 1);
    const int b   = bid >> 14;

    const int w = threadIdx.x & (WW - 1);
    const int h = (hp << 1) | (threadIdx.x >> 7);

    const float4 P = params[b * CH + c];      // {s*ca, s*sa, tx, ty}

    // depth coordinate: z = 2*c/255 - 1 ; iz = ((z+1)*256 - 1)/2
    const float iz  = ((512.0f / 255.0f) * (float)c - 1.0f) * 0.5f;
    const float z0f = floorf(iz);
    const float wz  = iz - z0f;
    const int   z0  = (int)z0f;
    const int   z1  = z0 + 1;

    // output-grid normalized coords (align_corners=True style)
    const float x = (2.0f / 127.0f) * (float)w - 1.0f;
    const float y = (2.0f / 127.0f) * (float)h - 1.0f;

    const float gx = P.x * x - P.y * y + P.z;
    const float gy = P.y * x + P.x * y + P.w;

    // unnormalize (align_corners=False): ix = ((gx+1)*W - 1)/2
    const float ix  = (gx * (float)WW + (float)(WW - 1)) * 0.5f;
    const float iy  = (gy * (float)HH + (float)(HH - 1)) * 0.5f;
    const float x0f = floorf(ix);
    const float y0f = floorf(iy);
    const float fx  = ix - x0f;
    const float fy  = iy - y0f;
    const int   x0  = (int)x0f, x1 = x0 + 1;
    const int   y0  = (int)y0f, y1 = y0 + 1;

    // zero-padding via weight masking; loads always use clamped indices
    const float wx0 = (x0 >= 0 && x0 < WW) ? (1.0f - fx) : 0.0f;
    const float wx1 = (x1 >= 0 && x1 < WW) ? fx          : 0.0f;
    const float wy0 = (y0 >= 0 && y0 < HH) ? (1.0f - fy) : 0.0f;
    const float wy1 = (y1 >= 0 && y1 < HH) ? fy          : 0.0f;
    const float wz0 = (z0 >= 0)            ? (1.0f - wz) : 0.0f;  // z0 <= 255 always
    const float wz1 = (z1 < CH)            ? wz          : 0.0f;  // z1 >= 0 always

    const int xc0 = min(max(x0, 0), WW - 1);
    const int xc1 = min(max(x1, 0), WW - 1);
    const int yc0 = min(max(y0, 0), HH - 1);
    const int yc1 = min(max(y1, 0), HH - 1);
    const int zc0 = min(max(z0, 0), CH - 1);
    const int zc1 = min(max(z1, 0), CH - 1);

    const float* base = fm + (size_t)b * CH * HH * WW;
    const float* p0   = base + (size_t)zc0 * HH * WW;
    const float* p1   = base + (size_t)zc1 * HH * WW;

    const int r0 = yc0 * WW;
    const int r1 = yc1 * WW;

    const float v000 = p0[r0 + xc0];
    const float v001 = p0[r0 + xc1];
    const float v010 = p0[r1 + xc0];
    const float v011 = p0[r1 + xc1];
    const float v100 = p1[r0 + xc0];
    const float v101 = p1[r0 + xc1];
    const float v110 = p1[r1 + xc0];
    const float v111 = p1[r1 + xc1];

    const float bil0 = wy0 * (wx0 * v000 + wx1 * v001) + wy1 * (wx0 * v010 + wx1 * v011);
    const float bil1 = wy0 * (wx0 * v100 + wx1 * v101) + wy1 * (wx0 * v110 + wx1 * v111);
    const float r    = wz0 * bil0 + wz1 * bil1;

    out[(((size_t)b * CH + c) * HH + h) * WW + w] = r;
}

// ---------------------------------------------------------------------------
extern "C" void kernel_launch(void* const* d_in, const int* in_sizes, int n_in,
                              void* d_out, int out_size, void* d_ws, size_t ws_size,
                              hipStream_t stream) {
    const float* feature_map = (const float*)d_in[0];  // [4,256,128,128]
    const float* para_code   = (const float*)d_in[1];  // [4,256]
    const float* W1 = (const float*)d_in[2];
    const float* b1 = (const float*)d_in[3];
    const float* Ws = (const float*)d_in[4];
    const float* bs = (const float*)d_in[5];
    const float* Wr = (const float*)d_in[6];
    const float* br = (const float*)d_in[7];
    const float* Wt = (const float*)d_in[8];
    const float* bt = (const float*)d_in[9];

    float4* params = (float4*)d_ws;   // BATCH*CH float4 = 16 KiB

    adaat_params_kernel<<<BATCH, 256, 0, stream>>>(
        para_code, W1, b1, Ws, bs, Wr, br, Wt, bt, params);

    const int nblocks = BATCH * CH * (HH / 2);   // 65536
    adaat_sample_kernel<<<nblocks, 256, 0, stream>>>(
        feature_map, params, (float*)d_out);
}

// Round 2
// 202.288 us; speedup vs baseline: 1.3082x; 1.3082x over previous
//
#include <hip/hip_runtime.h>
#include <math.h>

#define BATCH 4
#define CH    256   // feature channels == depth of sampled volume
#define HH    128
#define WW    128
#define PC    256   // para channels
#define PI_F  3.14159f

// ---------------------------------------------------------------------------
// Kernel A: p = relu(para_code @ W1 + b1)  -> p_ws[4][256]
// grid = 16 blocks (b*4 + jchunk), 256 threads = 64 j x 4 k-slices.
// ---------------------------------------------------------------------------
__global__ __launch_bounds__(256)
void adaat_p_kernel(const float* __restrict__ pc,
                    const float* __restrict__ W1, const float* __restrict__ b1,
                    float* __restrict__ p_out) {
    const int b  = blockIdx.x >> 2;
    const int jc = blockIdx.x & 3;
    const int jj = threadIdx.x & 63;
    const int kk = threadIdx.x >> 6;          // 0..3
    const int j  = jc * 64 + jj;

    const float* pcb = pc + b * PC + kk * 64;
    const float* w   = W1 + (kk * 64) * PC + j;

    float acc = 0.0f;
#pragma unroll 8
    for (int i = 0; i < 64; ++i)
        acc = fmaf(pcb[i], w[i * PC], acc);

    __shared__ float sh[256];
    sh[threadIdx.x] = acc;
    __syncthreads();
    if (kk == 0) {
        float s = sh[jj] + sh[64 + jj] + sh[128 + jj] + sh[192 + jj] + b1[j];
        p_out[b * PC + j] = fmaxf(s, 0.0f);
    }
}

// ---------------------------------------------------------------------------
// Kernel B: heads -> params[b*CH+c] = {s*cos, s*sin, tx, ty}
// Same decomposition as kernel A; 4 dot products per output channel.
// ---------------------------------------------------------------------------
__global__ __launch_bounds__(256)
void adaat_heads_kernel(const float* __restrict__ p_in,
                        const float* __restrict__ Ws, const float* __restrict__ bs,
                        const float* __restrict__ Wr, const float* __restrict__ br,
                        const float* __restrict__ Wt, const float* __restrict__ bt,
                        float4* __restrict__ params) {
    const int b  = blockIdx.x >> 2;
    const int jc = blockIdx.x & 3;
    const int jj = threadIdx.x & 63;
    const int kk = threadIdx.x >> 6;
    const int j  = jc * 64 + jj;

    const float*  pb  = p_in + b * PC + kk * 64;
    const float*  wsp = Ws + (kk * 64) * CH + j;
    const float*  wrp = Wr + (kk * 64) * CH + j;
    const float2* wtp = (const float2*)Wt + (kk * 64) * CH + j;  // row stride = 256 float2

    float as = 0.f, ar = 0.f, at0 = 0.f, at1 = 0.f;
#pragma unroll 4
    for (int i = 0; i < 64; ++i) {
        const float pk = pb[i];
        as  = fmaf(pk, wsp[i * CH], as);
        ar  = fmaf(pk, wrp[i * CH], ar);
        const float2 t = wtp[i * CH];
        at0 = fmaf(pk, t.x, at0);
        at1 = fmaf(pk, t.y, at1);
    }

    __shared__ float4 sh[256];
    sh[threadIdx.x] = make_float4(as, ar, at0, at1);
    __syncthreads();
    if (kk == 0) {
        const float4 a = sh[jj], b4 = sh[64 + jj], c4 = sh[128 + jj], d4 = sh[192 + jj];
        const float As = a.x + b4.x + c4.x + d4.x + bs[j];
        const float Ar = a.y + b4.y + c4.y + d4.y + br[j];
        const float T0 = a.z + b4.z + c4.z + d4.z + bt[2 * j];
        const float T1 = a.w + b4.w + c4.w + d4.w + bt[2 * j + 1];
        const float s   = 2.0f / (1.0f + expf(-As));
        const float ang = tanhf(Ar) * PI_F;
        float sa, ca;
        sincosf(ang, &sa, &ca);
        params[b * CH + j] = make_float4(s * ca, s * sa, tanhf(T0), tanhf(T1));
    }
}

// ---------------------------------------------------------------------------
// Kernel C: LDS-staged trilinear sampler.
// One block per (b,c): stage plane z0 into LDS (64 KiB, XOR-swizzled),
// gather bilinear for all 16K pixels (16 px/thread), then stage plane z1
// and accumulate. Swizzle addr = y*128 + ((x+y)&127):
//   row-walk (lanes vary x): stride 1  -> conflict-free
//   col-walk (lanes vary y): stride 129 -> conflict-free
// ---------------------------------------------------------------------------
__global__ __launch_bounds__(1024)
void adaat_sample_kernel(const float* __restrict__ fm,
                         const float4* __restrict__ params,
                         float* __restrict__ out) {
    __shared__ float lds[HH * WW];   // exactly 64 KiB

    const int bc = blockIdx.x;       // b*CH + c
    const int c  = bc & (CH - 1);
    const int b  = bc >> 8;
    const int t  = threadIdx.x;      // 0..1023

    // depth interpolation (uniform across block)
    const float iz  = (256.0f / 255.0f) * (float)c - 0.5f;
    const float z0f = floorf(iz);
    const float fz  = iz - z0f;
    const int   z0  = (int)z0f;
    const int   z1  = z0 + 1;
    const float wz0 = (z0 >= 0) ? (1.0f - fz) : 0.0f;
    const float wz1 = (z1 < CH) ? fz          : 0.0f;
    const int   zc0 = min(max(z0, 0), CH - 1);
    const int   zc1 = min(max(z1, 0), CH - 1);

    const float* base = fm + (size_t)b * (CH * HH * WW);
    const float* pg[2] = { base + (size_t)zc0 * (HH * WW),
                           base + (size_t)zc1 * (HH * WW) };
    const float  wzp[2] = { wz0, wz1 };

    const float4 P  = params[bc];    // {A=s*cos, B=s*sin, tx, ty}
    const float  A  = P.x, Bv = P.y, Tx = P.z, Ty = P.w;

    const int   w  = t & (WW - 1);
    const int   h0 = t >> 7;         // 0..7
    const float xg = (2.0f / 127.0f) * (float)w - 1.0f;
    float* outp = out + (size_t)bc * (HH * WW);

    float acc[16];

    for (int phase = 0; phase < 2; ++phase) {
        if (phase) __syncthreads();  // all reads of plane0 done before overwrite
        // stage plane: 16 floats/thread as 4 coalesced float4 loads
        const float* src = pg[phase];
#pragma unroll
        for (int i = 0; i < 4; ++i) {
            const int fi = 4 * (t + 1024 * i);
            const int y  = fi >> 7;
            const int x  = fi & (WW - 1);
            const float4 v = *(const float4*)(src + fi);
            const int row = y * WW;
            lds[row + ((x     + y) & 127)] = v.x;
            lds[row + ((x + 1 + y) & 127)] = v.y;
            lds[row + ((x + 2 + y) & 127)] = v.z;
            lds[row + ((x + 3 + y) & 127)] = v.w;
        }
        __syncthreads();

        const float wzk = wzp[phase];
#pragma unroll 4
        for (int k = 0; k < 16; ++k) {
            const int   h  = h0 + 8 * k;
            const float yg = (2.0f / 127.0f) * (float)h - 1.0f;
            const float gx = A * xg - Bv * yg + Tx;
            const float gy = Bv * xg + A * yg + Ty;
            // unnormalize (align_corners=False): ix = ((gx+1)*128 - 1)/2
            const float ixf = gx * 64.0f + 63.5f;
            const float iyf = gy * 64.0f + 63.5f;
            const float x0f = floorf(ixf);
            const float y0f = floorf(iyf);
            const float fx  = ixf - x0f;
            const float fy  = iyf - y0f;
            const int x0 = (int)x0f, x1i = x0 + 1;
            const int y0i = (int)y0f, y1i = y0i + 1;

            const float wx0 = (x0  >= 0 && x0  < WW) ? (1.0f - fx) : 0.0f;
            const float wx1 = (x1i >= 0 && x1i < WW) ? fx          : 0.0f;
            const float wy0 = (y0i >= 0 && y0i < HH) ? (1.0f - fy) : 0.0f;
            const float wy1 = (y1i >= 0 && y1i < HH) ? fy          : 0.0f;

            const int xc0 = min(max(x0, 0), WW - 1);
            const int xc1 = min(max(x1i, 0), WW - 1);
            const int yc0 = min(max(y0i, 0), HH - 1);
            const int yc1 = min(max(y1i, 0), HH - 1);

            const int r0 = yc0 * WW, r1 = yc1 * WW;
            const float v00 = lds[r0 + ((xc0 + yc0) & 127)];
            const float v01 = lds[r0 + ((xc1 + yc0) & 127)];
            const float v10 = lds[r1 + ((xc0 + yc1) & 127)];
            const float v11 = lds[r1 + ((xc1 + yc1) & 127)];

            const float bil = wy0 * (wx0 * v00 + wx1 * v01)
                            + wy1 * (wx0 * v10 + wx1 * v11);
            if (phase == 0) acc[k] = wzk * bil;
            else            acc[k] = fmaf(wzk, bil, acc[k]);
        }
    }

#pragma unroll
    for (int k = 0; k < 16; ++k)
        outp[(h0 + 8 * k) * WW + w] = acc[k];
}

// ---------------------------------------------------------------------------
extern "C" void kernel_launch(void* const* d_in, const int* in_sizes, int n_in,
                              void* d_out, int out_size, void* d_ws, size_t ws_size,
                              hipStream_t stream) {
    const float* feature_map = (const float*)d_in[0];  // [4,256,128,128]
    const float* para_code   = (const float*)d_in[1];  // [4,256]
    const float* W1 = (const float*)d_in[2];
    const float* b1 = (const float*)d_in[3];
    const float* Ws = (const float*)d_in[4];
    const float* bs = (const float*)d_in[5];
    const float* Wr = (const float*)d_in[6];
    const float* br = (const float*)d_in[7];
    const float* Wt = (const float*)d_in[8];
    const float* bt = (const float*)d_in[9];

    float*  p_ws   = (float*)d_ws;                       // 4*256 floats = 4 KiB
    float4* params = (float4*)((char*)d_ws + 4096);      // 4*256 float4 = 16 KiB

    adaat_p_kernel<<<16, 256, 0, stream>>>(para_code, W1, b1, p_ws);
    adaat_heads_kernel<<<16, 256, 0, stream>>>(p_ws, Ws, bs, Wr, br, Wt, bt, params);
    adaat_sample_kernel<<<BATCH * CH, 1024, 0, stream>>>(feature_map, params, (float*)d_out);
}